// Round 1
// baseline (37.087 us; speedup 1.0000x reference)
//
#include <hip/hip_runtime.h>

#define B_ 2
#define H_ 352
#define W_ 1216
#define HW_ (H_ * W_)      // 428032
#define K_ 9
#define NPIX (B_ * HW_)    // 856064 = 3344 * 256

__global__ __launch_bounds__(256) void dcn_post_kernel(
    const float* __restrict__ depth,
    const float* __restrict__ weight,
    const float* __restrict__ offset,
    const float* __restrict__ wtap,
    const float* __restrict__ bias,
    float* __restrict__ out)
{
    const int t = blockIdx.x * 256 + threadIdx.x;   // global pixel id, exact grid
    const int b = t / HW_;
    const int p = t - b * HW_;
    const int y = p / W_;
    const int x = p - y * W_;

    const float* __restrict__ dpt = depth + b * HW_;
    const float dval = dpt[p];

    // mask weights: 9 coalesced plane loads + mean
    float wg[K_];
    float m = 0.f;
    const float* wbase = weight + (size_t)b * K_ * HW_ + p;
#pragma unroll
    for (int k = 0; k < K_; ++k) {
        wg[k] = wbase[k * HW_];
        m += wg[k];
    }
    m *= (1.f / 9.f);

    const float* obase = offset + (size_t)b * 2 * K_ * HW_ + p;

    float acc = 0.f;
#pragma unroll
    for (int k = 0; k < K_; ++k) {
        const float dy = obase[(2 * k) * HW_];
        const float dx = obase[(2 * k + 1) * HW_];
        const float py = (float)(y + (k / 3) - 1) + dy;
        const float px = (float)(x + (k % 3) - 1) + dx;
        const float y0f = floorf(py);
        const float x0f = floorf(px);
        const float fy = py - y0f;
        const float fx = px - x0f;
        const int y0 = (int)y0f, x0 = (int)x0f;
        const int y1 = y0 + 1,  x1 = x0 + 1;
        const bool vy0 = (unsigned)y0 < (unsigned)H_;
        const bool vy1 = (unsigned)y1 < (unsigned)H_;
        const bool vx0 = (unsigned)x0 < (unsigned)W_;
        const bool vx1 = (unsigned)x1 < (unsigned)W_;
        const int ry0 = y0 * W_;
        const int ry1 = y1 * W_;
        const float v00 = (vy0 && vx0) ? dpt[ry0 + x0] : 0.f;
        const float v01 = (vy0 && vx1) ? dpt[ry0 + x1] : 0.f;
        const float v10 = (vy1 && vx0) ? dpt[ry1 + x0] : 0.f;
        const float v11 = (vy1 && vx1) ? dpt[ry1 + x1] : 0.f;
        const float gy = 1.f - fy, gx = 1.f - fx;
        const float val = v00 * gy * gx + v01 * gy * fx
                        + v10 * fy * gx + v11 * fy * fx;
        acc += (wg[k] - m) * wtap[k] * val;
    }

    out[t] = acc + bias[0] + dval;
}

extern "C" void kernel_launch(void* const* d_in, const int* in_sizes, int n_in,
                              void* d_out, int out_size, void* d_ws, size_t ws_size,
                              hipStream_t stream) {
    const float* depth  = (const float*)d_in[0];
    const float* weight = (const float*)d_in[1];
    const float* offset = (const float*)d_in[2];
    const float* wtap   = (const float*)d_in[3];
    const float* bias   = (const float*)d_in[4];
    float* out = (float*)d_out;

    dim3 grid(NPIX / 256), block(256);
    hipLaunchKernelGGL(dcn_post_kernel, grid, block, 0, stream,
                       depth, weight, offset, wtap, bias, out);
}